// Round 13
// baseline (369.219 us; speedup 1.0000x reference)
//
#include <hip/hip_runtime.h>
#include <stdint.h>

typedef float f32x4 __attribute__((ext_vector_type(4)));
typedef short bf16x8 __attribute__((ext_vector_type(8)));

constexpr int NB = 4;      // batch
constexpr int NS = 2048;   // sequence
constexpr int ND = 512;    // model dim
constexpr int NH = 8;      // heads
constexpr int NDK = 64;    // head dim
constexpr int NT = NS / 64;  // 32 K-tiles
constexpr float QSCALE = 0.125f * 1.44269504088896340736f;  // 1/sqrt(dk) * log2(e)

static __device__ __forceinline__ unsigned short f2bf(float f) {
    union { float f; uint32_t u; } v; v.f = f;
    uint32_t r = (v.u + 0x7FFFu + ((v.u >> 16) & 1u)) >> 16;
    return (unsigned short)r;
}
static __device__ __forceinline__ uint32_t pkbf(float a, float b) {
    union { float f; uint32_t u; } x, y; x.f = a; y.f = b;
    return ((x.u + 0x8000u) >> 16) | (((y.u + 0x8000u) >> 16) << 16);
}
static __device__ __forceinline__ float exp2_fast(float x) {
#if __has_builtin(__builtin_amdgcn_exp2f)
    return __builtin_amdgcn_exp2f(x);
#else
    return exp2f(x);
#endif
}

// async global->LDS, 16B per lane; dest is wave-uniform base (+lane*16 by HW)
static __device__ __forceinline__ void gload_lds16(const void* g, void* l) {
    __builtin_amdgcn_global_load_lds((const __attribute__((address_space(1))) void*)g,
                                     (__attribute__((address_space(3))) void*)l, 16, 0, 0);
}

// ---------------- fp32 -> bf16 convert (3 tensors fused) ----------------
__global__ __launch_bounds__(256) void cvt3_kernel(const float4* __restrict__ a,
                                                   const float4* __restrict__ b,
                                                   const float4* __restrict__ c,
                                                   ushort4* __restrict__ oa,
                                                   ushort4* __restrict__ ob,
                                                   ushort4* __restrict__ oc, int n4) {
    int which = blockIdx.y;
    const float4* in = which == 0 ? a : which == 1 ? b : c;
    ushort4* out = which == 0 ? oa : which == 1 ? ob : oc;
    int i = blockIdx.x * blockDim.x + threadIdx.x;
    if (i >= n4) return;
    float4 v = in[i];
    ushort4 o;
    o.x = f2bf(v.x); o.y = f2bf(v.y); o.z = f2bf(v.z); o.w = f2bf(v.w);
    out[i] = o;
}

// ---------------- mask int32 -> bitmask (1 bit per element) ----------------
__global__ __launch_bounds__(256) void bitmask_kernel(const int* __restrict__ mask,
                                                      unsigned long long* __restrict__ bm,
                                                      int nwords) {
    int lane = threadIdx.x & 63;
    int wave = threadIdx.x >> 6;
    int wgid = blockIdx.x * 4 + wave;
    int nw = gridDim.x * 4;
    for (int c = wgid; c < nwords; c += nw) {
        int v = mask[(size_t)c * 64 + lane];
        unsigned long long bits = __ballot(v != 0);
        if (lane == 0) bm[c] = bits;
    }
}

// ---------------- fused projections: z=0 Q (scale QSCALE), z=1 K, z=2 V (transposed out) -----
__global__ __launch_bounds__(256) void proj_kernel(const unsigned short* __restrict__ xq,
                                                   const unsigned short* __restrict__ xk,
                                                   const unsigned short* __restrict__ xv,
                                                   const unsigned short* __restrict__ wq,
                                                   const unsigned short* __restrict__ wk,
                                                   const unsigned short* __restrict__ wv,
                                                   const float* __restrict__ bq,
                                                   const float* __restrict__ bk,
                                                   const float* __restrict__ bv,
                                                   unsigned short* __restrict__ Qw,
                                                   unsigned short* __restrict__ Kw,
                                                   unsigned short* __restrict__ VTw) {
    int z = blockIdx.z;
    const unsigned short* X = z == 0 ? xq : z == 1 ? xk : xv;
    const unsigned short* W = z == 0 ? wq : z == 1 ? wk : wv;
    const float* bias = z == 0 ? bq : z == 1 ? bk : bv;
    unsigned short* out = z == 0 ? Qw : z == 1 ? Kw : VTw;
    float scale = z == 0 ? QSCALE : 1.0f;
    int vtrans = (z == 2);

    int lane = threadIdx.x & 63;
    int wave = threadIdx.x >> 6;
    int lrow = lane & 15, lgrp = lane >> 4;
    int m0 = blockIdx.x * 64 + wave * 16;
    int n0 = blockIdx.y * 64;

    f32x4 acc[4] = {{0.f,0.f,0.f,0.f},{0.f,0.f,0.f,0.f},{0.f,0.f,0.f,0.f},{0.f,0.f,0.f,0.f}};
    const unsigned short* xrow = X + (size_t)(m0 + lrow) * ND;
    for (int k = 0; k < ND; k += 32) {
        bf16x8 a = *(const bf16x8*)(xrow + k + lgrp * 8);
#pragma unroll
        for (int n = 0; n < 4; n++) {
            bf16x8 b = *(const bf16x8*)(W + (size_t)(n0 + n * 16 + lrow) * ND + k + lgrp * 8);
            acc[n] = __builtin_amdgcn_mfma_f32_16x16x32_bf16(a, b, acc[n], 0, 0, 0);
        }
    }
#pragma unroll
    for (int n = 0; n < 4; n++) {
        int col = n0 + n * 16 + lrow;
        int h = col >> 6, d = col & 63;
        float bv_ = bias[col];
#pragma unroll
        for (int j = 0; j < 4; j++) {
            int m = m0 + lgrp * 4 + j;
            int bidx = m >> 11, s = m & (NS - 1);
            float y = (acc[n][j] + bv_) * scale;
            size_t off = vtrans ? ((size_t)(bidx * NH + h) * NDK + d) * NS + s
                                : ((size_t)(bidx * NH + h) * NS + s) * NDK + d;
            out[off] = f2bf(y);
        }
    }
}

// ---------------- attention ----------------
// 256 threads = 4 waves; block owns 64 q-rows, full K range; 4 blocks/CU (40KB LDS).
// Q pre-scaled by log2e/8. SWAPPED QK^T: lane holds qi = lane&15 fixed, ki = n*16+lgrp*4+j.
// kv[4] buffer pool: sweep 1 = 4-deep K ring, 2 tiles per barrier phase; sweep 2 =
// K dbuf kv[0/1] + V dbuf kv[2/3]. XOR-swizzled staging. Raw s_barrier + counted vmcnt.
// attn stores are PLAIN (not nontemporal): the 4 x 64B per-row pieces must write-allocate
// in L2 so they merge into full lines (nt caused ~17% partial-line write overhead).
__global__ __launch_bounds__(256) void attn_kernel(const unsigned short* __restrict__ Q,
                                                   const unsigned short* __restrict__ K,
                                                   const unsigned short* __restrict__ VT,
                                                   const unsigned long long* __restrict__ bm,
                                                   float* __restrict__ attn_out,
                                                   float* __restrict__ Ob) {
    __shared__ __align__(16) unsigned short kv[4][64 * 64];   // 32KB buffer pool
    __shared__ __align__(16) unsigned short pl[4][16][64];    // 8KB per-wave P tile, XOR-swizzled

    int lane = threadIdx.x & 63;
    int wave = threadIdx.x >> 6;      // 0..3
    int lrow = lane & 15, lgrp = lane >> 4;

    // XCD-aware remap: id&7 = xcd, 4 bh per xcd, 32 q-blocks per bh
    int id = blockIdx.x;
    int xcd = id & 7;
    int loc = id >> 3;            // 0..127
    int bh = xcd * 4 + (loc >> 5);
    int qb = loc & 31;
    int b = bh >> 3, h = bh & 7;
    int qw = qb * 64 + wave * 16;   // this wave's 16 q rows

    const unsigned short* qrow = Q + ((size_t)bh * NS + qw + lrow) * NDK + lgrp * 8;
    bf16x8 aq0 = *(const bf16x8*)(qrow);
    bf16x8 aq1 = *(const bf16x8*)(qrow + 32);

    const unsigned short* kbase = K + (size_t)bh * NS * NDK;
    const unsigned short* vbase = VT + (size_t)bh * NDK * NS;
    const unsigned long long* bmrow = bm + ((size_t)b * NS + qw + lrow) * (NS / 64);

    int rl = lane >> 3, cc = lane & 7;      // staging: slab row (0..7), chunk (0..7)
    int cs = (cc ^ rl) * 8;                 // swizzled source chunk offset (ushorts)
    int r0 = 16 * wave + rl;                // this wave's staging rows: r0 and r0+8
    int plsw = (lrow & 7) << 3;             // pl XOR swizzle (ushort units, 16B granules)

    // ---- sweep 1: l = sum of unmasked exp2(sc); 2 tiles per barrier phase ----
    gload_lds16(kbase + (size_t)r0 * NDK + cs, &kv[0][(16 * wave) * 64]);
    gload_lds16(kbase + (size_t)(r0 + 8) * NDK + cs, &kv[0][(16 * wave + 8) * 64]);
    gload_lds16(kbase + (size_t)(64 + r0) * NDK + cs, &kv[1][(16 * wave) * 64]);
    gload_lds16(kbase + (size_t)(64 + r0 + 8) * NDK + cs, &kv[1][(16 * wave + 8) * 64]);
    unsigned long long wcA = bmrow[0], wcB = bmrow[1];
    asm volatile("s_waitcnt vmcnt(2)" ::: "memory");   // force the 4 K staging calls
    __builtin_amdgcn_s_barrier();

    float lacc = 0.f;
    for (int sp = 0; sp < NT / 2; sp++) {
        int bufA = (2 * sp) & 3, bufB = (2 * sp + 1) & 3;
        unsigned long long wnA = 0, wnB = 0;
        if (sp + 1 < NT / 2) {
            const unsigned short* ka = kbase + (size_t)((2 * sp + 2) * 64) * NDK;
            const unsigned short* kb2 = kbase + (size_t)((2 * sp + 3) * 64) * NDK;
            gload_lds16(ka + (size_t)r0 * NDK + cs, &kv[bufA ^ 2][(16 * wave) * 64]);
            gload_lds16(ka + (size_t)(r0 + 8) * NDK + cs, &kv[bufA ^ 2][(16 * wave + 8) * 64]);
            gload_lds16(kb2 + (size_t)r0 * NDK + cs, &kv[bufB ^ 2][(16 * wave) * 64]);
            gload_lds16(kb2 + (size_t)(r0 + 8) * NDK + cs, &kv[bufB ^ 2][(16 * wave + 8) * 64]);
            wnA = bmrow[2 * sp + 2];
            wnB = bmrow[2 * sp + 3];
        }
#pragma unroll
        for (int half = 0; half < 2; half++) {
            int buf = half == 0 ? bufA : bufB;
            unsigned long long w = half == 0 ? wcA : wcB;
            f32x4 sc[4] = {{0.f,0.f,0.f,0.f},{0.f,0.f,0.f,0.f},{0.f,0.f,0.f,0.f},{0.f,0.f,0.f,0.f}};
            __builtin_amdgcn_s_setprio(1);
#pragma unroll
            for (int n = 0; n < 4; n++) {
                int R = n * 16 + lrow;
                bf16x8 b0 = *(const bf16x8*)&kv[buf][R * 64 + ((lgrp ^ (lrow & 7)) * 8)];
                bf16x8 b1 = *(const bf16x8*)&kv[buf][R * 64 + (((4 + lgrp) ^ (lrow & 7)) * 8)];
                sc[n] = __builtin_amdgcn_mfma_f32_16x16x32_bf16(b0, aq0, sc[n], 0, 0, 0);
                sc[n] = __builtin_amdgcn_mfma_f32_16x16x32_bf16(b1, aq1, sc[n], 0, 0, 0);
            }
            __builtin_amdgcn_s_setprio(0);
            uint32_t wlo = (uint32_t)w, whi = (uint32_t)(w >> 32);
#pragma unroll
            for (int n = 0; n < 4; n++)
#pragma unroll
                for (int j = 0; j < 4; j++) {
                    uint32_t bit = ((n < 2 ? wlo : whi) >> ((n & 1) * 16 + lgrp * 4 + j)) & 1u;
                    float e = exp2_fast(sc[n][j]);
                    lacc += bit ? 0.f : e;
                }
        }
        wcA = wnA; wcB = wnB;
        if (sp + 1 < NT / 2) {
            asm volatile("s_waitcnt vmcnt(2)" ::: "memory");  // force K x4; leave wnA,wnB
            __builtin_amdgcn_s_barrier();
        }
    }
    lacc += __shfl_xor(lacc, 16);
    lacc += __shfl_xor(lacc, 32);
    float li = -__log2f(lacc);

    // ---- sweep 2: recompute, write normalized attn, accumulate O ----
    // K double-buffer in kv[0/1], V double-buffer in kv[2/3]
    gload_lds16(kbase + (size_t)r0 * NDK + cs, &kv[0][(16 * wave) * 64]);
    gload_lds16(kbase + (size_t)(r0 + 8) * NDK + cs, &kv[0][(16 * wave + 8) * 64]);
    gload_lds16(vbase + (size_t)r0 * NS + cs, &kv[2][(16 * wave) * 64]);
    gload_lds16(vbase + (size_t)(r0 + 8) * NS + cs, &kv[2][(16 * wave + 8) * 64]);
    unsigned long long wc = bmrow[0], wn = 0;
    asm volatile("s_waitcnt vmcnt(1)" ::: "memory");   // force the 4 staging calls; wc floats
    __builtin_amdgcn_s_barrier();

    f32x4 accO[4] = {{0.f,0.f,0.f,0.f},{0.f,0.f,0.f,0.f},{0.f,0.f,0.f,0.f},{0.f,0.f,0.f,0.f}};
    float* arow = attn_out + (size_t)bh * NS * NS + (size_t)(qw + lrow) * NS;

    for (int t = 0; t < NT; t++) {
        int buf = t & 1;
        int kt = t * 64;
        if (t + 1 < NT) {
            const unsigned short* kt1 = kbase + (size_t)((t + 1) * 64) * NDK;
            gload_lds16(kt1 + (size_t)r0 * NDK + cs, &kv[buf ^ 1][(16 * wave) * 64]);
            gload_lds16(kt1 + (size_t)(r0 + 8) * NDK + cs, &kv[buf ^ 1][(16 * wave + 8) * 64]);
            const unsigned short* vt1 = vbase + (t + 1) * 64;
            gload_lds16(vt1 + (size_t)r0 * NS + cs, &kv[2 + (buf ^ 1)][(16 * wave) * 64]);
            gload_lds16(vt1 + (size_t)(r0 + 8) * NS + cs, &kv[2 + (buf ^ 1)][(16 * wave + 8) * 64]);
            wn = bmrow[t + 1];
        }
        f32x4 sc[4] = {{0.f,0.f,0.f,0.f},{0.f,0.f,0.f,0.f},{0.f,0.f,0.f,0.f},{0.f,0.f,0.f,0.f}};
        __builtin_amdgcn_s_setprio(1);
#pragma unroll
        for (int n = 0; n < 4; n++) {
            int R = n * 16 + lrow;
            bf16x8 b0 = *(const bf16x8*)&kv[buf][R * 64 + ((lgrp ^ (lrow & 7)) * 8)];
            bf16x8 b1 = *(const bf16x8*)&kv[buf][R * 64 + (((4 + lgrp) ^ (lrow & 7)) * 8)];
            sc[n] = __builtin_amdgcn_mfma_f32_16x16x32_bf16(b0, aq0, sc[n], 0, 0, 0);  // swapped
            sc[n] = __builtin_amdgcn_mfma_f32_16x16x32_bf16(b1, aq1, sc[n], 0, 0, 0);
        }
        __builtin_amdgcn_s_setprio(0);
        uint32_t wlo = (uint32_t)wc, whi = (uint32_t)(wc >> 32);
#pragma unroll
        for (int n = 0; n < 4; n++) {
            float p0, p1, p2, p3;
            uint32_t wsel = (n < 2) ? wlo : whi;
            int base = (n & 1) * 16 + lgrp * 4;
            p0 = ((wsel >> (base + 0)) & 1u) ? 0.f : exp2_fast(sc[n][0] + li);
            p1 = ((wsel >> (base + 1)) & 1u) ? 0.f : exp2_fast(sc[n][1] + li);
            p2 = ((wsel >> (base + 2)) & 1u) ? 0.f : exp2_fast(sc[n][2] + li);
            p3 = ((wsel >> (base + 3)) & 1u) ? 0.f : exp2_fast(sc[n][3] + li);
            f32x4 pv4 = {p0, p1, p2, p3};
            *(f32x4*)(arow + kt + n * 16 + lgrp * 4) = pv4;   // plain store: L2 merges lines
            uint2 pk = {pkbf(p0, p1), pkbf(p2, p3)};
            *(uint2*)&pl[wave][lrow][(n * 16 + lgrp * 4) ^ plsw] = pk;
        }
        __builtin_amdgcn_s_setprio(1);
#pragma unroll
        for (int step = 0; step < 2; step++) {
            bf16x8 ap = *(const bf16x8*)&pl[wave][lrow][(step * 32 + lgrp * 8) ^ plsw];
#pragma unroll
            for (int n = 0; n < 4; n++) {
                int R = n * 16 + lrow;
                bf16x8 bv = *(const bf16x8*)&kv[2 + buf][R * 64 + (((4 * step + lgrp) ^ (lrow & 7)) * 8)];
                accO[n] = __builtin_amdgcn_mfma_f32_16x16x32_bf16(ap, bv, accO[n], 0, 0, 0);
            }
        }
        __builtin_amdgcn_s_setprio(0);
        wc = wn;
        if (t + 1 < NT) {
            // queue: [K x2, V x2, wn, 4 stores] -> force the 4 staging loads, leave wn + stores
            asm volatile("s_waitcnt vmcnt(5)" ::: "memory");
            __builtin_amdgcn_s_barrier();
        }
    }

#pragma unroll
    for (int n = 0; n < 4; n++)
#pragma unroll
        for (int j = 0; j < 4; j++) {
            int qi = qw + lgrp * 4 + j;
            Ob[((size_t)b * NS + qi) * ND + h * NDK + n * 16 + lrow] = accO[n][j];
        }
}

// ---------------- residual + LayerNorm (OpenNMT: unbiased std, eps on std) ----------------
__global__ __launch_bounds__(256) void ln_kernel(const float* __restrict__ Ob,
                                                 const float* __restrict__ query,
                                                 const float* __restrict__ a2,
                                                 const float* __restrict__ b2,
                                                 float* __restrict__ out) {
    int row = blockIdx.x * 4 + (threadIdx.x >> 6);
    int lane = threadIdx.x & 63;
    const float4* orow = (const float4*)(Ob + (size_t)row * ND);
    const float4* qrow = (const float4*)(query + (size_t)row * ND);
    float4 v[2];
    float sum = 0.f;
#pragma unroll
    for (int t = 0; t < 2; t++) {
        float4 o = orow[lane + t * 64];
        float4 q = qrow[lane + t * 64];
        v[t].x = o.x + q.x; v[t].y = o.y + q.y; v[t].z = o.z + q.z; v[t].w = o.w + q.w;
        sum += v[t].x + v[t].y + v[t].z + v[t].w;
    }
#pragma unroll
    for (int s = 1; s < 64; s <<= 1) sum += __shfl_xor(sum, s);
    float mu = sum * (1.f / ND);
    float sq = 0.f;
#pragma unroll
    for (int t = 0; t < 2; t++) {
        float dx = v[t].x - mu, dy = v[t].y - mu, dz = v[t].z - mu, dw = v[t].w - mu;
        sq += dx * dx + dy * dy + dz * dz + dw * dw;
    }
#pragma unroll
    for (int s = 1; s < 64; s <<= 1) sq += __shfl_xor(sq, s);
    float var = sq * (1.f / (ND - 1));
    float inv = 1.f / (sqrtf(var) + 1e-6f);
    float4* orow_out = (float4*)(out + (size_t)row * ND);
#pragma unroll
    for (int t = 0; t < 2; t++) {
        float4 g = ((const float4*)a2)[lane + t * 64];
        float4 bb = ((const float4*)b2)[lane + t * 64];
        float4 r;
        r.x = g.x * (v[t].x - mu) * inv + bb.x;
        r.y = g.y * (v[t].y - mu) * inv + bb.y;
        r.z = g.z * (v[t].z - mu) * inv + bb.z;
        r.w = g.w * (v[t].w - mu) * inv + bb.w;
        orow_out[lane + t * 64] = r;
    }
}

extern "C" void kernel_launch(void* const* d_in, const int* in_sizes, int n_in,
                              void* d_out, int out_size, void* d_ws, size_t ws_size,
                              hipStream_t stream) {
    const float* key   = (const float*)d_in[0];
    const float* value = (const float*)d_in[1];
    const float* query = (const float*)d_in[2];
    const int*   mask  = (const int*)d_in[3];
    const float* Wk = (const float*)d_in[4];
    const float* bk = (const float*)d_in[5];
    const float* Wv = (const float*)d_in[6];
    const float* bv = (const float*)d_in[7];
    const float* Wq = (const float*)d_in[8];
    const float* bq = (const float*)d_in[9];
    const float* a2 = (const float*)d_in[10];
    const float* b2 = (const float*)d_in[11];

    const size_t nX = (size_t)NB * NS * ND;   // 4,194,304
    const size_t nW = (size_t)ND * ND;        // 262,144
    const int    nBMw = NB * NS * NS / 64;    // 262,144 uint64 words

    unsigned short* xq  = (unsigned short*)d_ws;  // bf16 buffers
    unsigned short* xk  = xq + nX;
    unsigned short* xv  = xk + nX;
    unsigned short* wqb = xv + nX;
    unsigned short* wkb = wqb + nW;
    unsigned short* wvb = wkb + nW;
    unsigned short* Qw  = wvb + nW;               // [BH][S][dk]
    unsigned short* Kw  = Qw + nX;                // [BH][S][dk]
    unsigned short* VTw = Kw + nX;                // [BH][dk][S]
    float* Ow = (float*)(VTw + nX);               // [B][S][D] fp32
    unsigned long long* bmw = (unsigned long long*)(Ow + nX);  // bitmask, 2 MB

    bitmask_kernel<<<2048, 256, 0, stream>>>(mask, bmw, nBMw);

    cvt3_kernel<<<dim3((int)(nX / 4 / 256), 3), 256, 0, stream>>>(
        (const float4*)query, (const float4*)key, (const float4*)value,
        (ushort4*)xq, (ushort4*)xk, (ushort4*)xv, (int)(nX / 4));
    cvt3_kernel<<<dim3((int)(nW / 4 / 256), 3), 256, 0, stream>>>(
        (const float4*)Wq, (const float4*)Wk, (const float4*)Wv,
        (ushort4*)wqb, (ushort4*)wkb, (ushort4*)wvb, (int)(nW / 4));

    proj_kernel<<<dim3(128, 8, 3), 256, 0, stream>>>(xq, xk, xv, wqb, wkb, wvb,
                                                     bq, bk, bv, Qw, Kw, VTw);

    float* attn_out = (float*)d_out + nX;  // res occupies first nX floats
    attn_kernel<<<1024, 256, 0, stream>>>(Qw, Kw, VTw, bmw, attn_out, Ow);

    ln_kernel<<<2048, 256, 0, stream>>>(Ow, query, a2, b2, (float*)d_out);
}

// Round 14
// 346.103 us; speedup vs baseline: 1.0668x; 1.0668x over previous
//
#include <hip/hip_runtime.h>
#include <stdint.h>

typedef float f32x4 __attribute__((ext_vector_type(4)));
typedef short bf16x8 __attribute__((ext_vector_type(8)));

constexpr int NB = 4;      // batch
constexpr int NS = 2048;   // sequence
constexpr int ND = 512;    // model dim
constexpr int NH = 8;      // heads
constexpr int NDK = 64;    // head dim
constexpr int NT = NS / 64;  // 32 K-tiles
constexpr float QSCALE = 0.125f * 1.44269504088896340736f;  // 1/sqrt(dk) * log2(e)

static __device__ __forceinline__ unsigned short f2bf(float f) {
    union { float f; uint32_t u; } v; v.f = f;
    uint32_t r = (v.u + 0x7FFFu + ((v.u >> 16) & 1u)) >> 16;
    return (unsigned short)r;
}
static __device__ __forceinline__ uint32_t pkbf(float a, float b) {
    union { float f; uint32_t u; } x, y; x.f = a; y.f = b;
    return ((x.u + 0x8000u) >> 16) | (((y.u + 0x8000u) >> 16) << 16);
}
static __device__ __forceinline__ float exp2_fast(float x) {
#if __has_builtin(__builtin_amdgcn_exp2f)
    return __builtin_amdgcn_exp2f(x);
#else
    return exp2f(x);
#endif
}

// async global->LDS, 16B per lane; dest is wave-uniform base (+lane*16 by HW)
static __device__ __forceinline__ void gload_lds16(const void* g, void* l) {
    __builtin_amdgcn_global_load_lds((const __attribute__((address_space(1))) void*)g,
                                     (__attribute__((address_space(3))) void*)l, 16, 0, 0);
}

// ---------------- fp32 -> bf16 convert (3 tensors fused) ----------------
__global__ __launch_bounds__(256) void cvt3_kernel(const float4* __restrict__ a,
                                                   const float4* __restrict__ b,
                                                   const float4* __restrict__ c,
                                                   ushort4* __restrict__ oa,
                                                   ushort4* __restrict__ ob,
                                                   ushort4* __restrict__ oc, int n4) {
    int which = blockIdx.y;
    const float4* in = which == 0 ? a : which == 1 ? b : c;
    ushort4* out = which == 0 ? oa : which == 1 ? ob : oc;
    int i = blockIdx.x * blockDim.x + threadIdx.x;
    if (i >= n4) return;
    float4 v = in[i];
    ushort4 o;
    o.x = f2bf(v.x); o.y = f2bf(v.y); o.z = f2bf(v.z); o.w = f2bf(v.w);
    out[i] = o;
}

// ---------------- mask int32 -> bitmask (1 bit per element) ----------------
__global__ __launch_bounds__(256) void bitmask_kernel(const int* __restrict__ mask,
                                                      unsigned long long* __restrict__ bm,
                                                      int nwords) {
    int lane = threadIdx.x & 63;
    int wave = threadIdx.x >> 6;
    int wgid = blockIdx.x * 4 + wave;
    int nw = gridDim.x * 4;
    for (int c = wgid; c < nwords; c += nw) {
        int v = mask[(size_t)c * 64 + lane];
        unsigned long long bits = __ballot(v != 0);
        if (lane == 0) bm[c] = bits;
    }
}

// ---------------- fused projections: z=0 Q (scale QSCALE), z=1 K, z=2 V (transposed out) -----
__global__ __launch_bounds__(256) void proj_kernel(const unsigned short* __restrict__ xq,
                                                   const unsigned short* __restrict__ xk,
                                                   const unsigned short* __restrict__ xv,
                                                   const unsigned short* __restrict__ wq,
                                                   const unsigned short* __restrict__ wk,
                                                   const unsigned short* __restrict__ wv,
                                                   const float* __restrict__ bq,
                                                   const float* __restrict__ bk,
                                                   const float* __restrict__ bv,
                                                   unsigned short* __restrict__ Qw,
                                                   unsigned short* __restrict__ Kw,
                                                   unsigned short* __restrict__ VTw) {
    int z = blockIdx.z;
    const unsigned short* X = z == 0 ? xq : z == 1 ? xk : xv;
    const unsigned short* W = z == 0 ? wq : z == 1 ? wk : wv;
    const float* bias = z == 0 ? bq : z == 1 ? bk : bv;
    unsigned short* out = z == 0 ? Qw : z == 1 ? Kw : VTw;
    float scale = z == 0 ? QSCALE : 1.0f;
    int vtrans = (z == 2);

    int lane = threadIdx.x & 63;
    int wave = threadIdx.x >> 6;
    int lrow = lane & 15, lgrp = lane >> 4;
    int m0 = blockIdx.x * 64 + wave * 16;
    int n0 = blockIdx.y * 64;

    f32x4 acc[4] = {{0.f,0.f,0.f,0.f},{0.f,0.f,0.f,0.f},{0.f,0.f,0.f,0.f},{0.f,0.f,0.f,0.f}};
    const unsigned short* xrow = X + (size_t)(m0 + lrow) * ND;
    for (int k = 0; k < ND; k += 32) {
        bf16x8 a = *(const bf16x8*)(xrow + k + lgrp * 8);
#pragma unroll
        for (int n = 0; n < 4; n++) {
            bf16x8 b = *(const bf16x8*)(W + (size_t)(n0 + n * 16 + lrow) * ND + k + lgrp * 8);
            acc[n] = __builtin_amdgcn_mfma_f32_16x16x32_bf16(a, b, acc[n], 0, 0, 0);
        }
    }
#pragma unroll
    for (int n = 0; n < 4; n++) {
        int col = n0 + n * 16 + lrow;
        int h = col >> 6, d = col & 63;
        float bv_ = bias[col];
#pragma unroll
        for (int j = 0; j < 4; j++) {
            int m = m0 + lgrp * 4 + j;
            int bidx = m >> 11, s = m & (NS - 1);
            float y = (acc[n][j] + bv_) * scale;
            size_t off = vtrans ? ((size_t)(bidx * NH + h) * NDK + d) * NS + s
                                : ((size_t)(bidx * NH + h) * NS + s) * NDK + d;
            out[off] = f2bf(y);
        }
    }
}

// ---------------- attention ----------------
// 256 threads = 4 waves; block owns 64 q-rows, full K range; 4 blocks/CU (40KB LDS).
// Q pre-scaled by log2e/8. SWAPPED QK^T: lane holds qi = lane&15 fixed, ki = n*16+lgrp*4+j.
// kv[4] buffer pool: sweep 1 = 4-deep K ring, 2 tiles per barrier phase; sweep 2 =
// K dbuf kv[0/1] + V dbuf kv[2/3]. XOR-swizzled staging. Raw s_barrier + counted vmcnt.
// attn stores NONTEMPORAL: no-allocate protects per-XCD L2 K/V residency (round-13 A/B:
// plain stores +22us despite line-merge benefit).
__global__ __launch_bounds__(256) void attn_kernel(const unsigned short* __restrict__ Q,
                                                   const unsigned short* __restrict__ K,
                                                   const unsigned short* __restrict__ VT,
                                                   const unsigned long long* __restrict__ bm,
                                                   float* __restrict__ attn_out,
                                                   float* __restrict__ Ob) {
    __shared__ __align__(16) unsigned short kv[4][64 * 64];   // 32KB buffer pool
    __shared__ __align__(16) unsigned short pl[4][16][64];    // 8KB per-wave P tile, XOR-swizzled

    int lane = threadIdx.x & 63;
    int wave = threadIdx.x >> 6;      // 0..3
    int lrow = lane & 15, lgrp = lane >> 4;

    // XCD-aware remap: id&7 = xcd, 4 bh per xcd, 32 q-blocks per bh
    int id = blockIdx.x;
    int xcd = id & 7;
    int loc = id >> 3;            // 0..127
    int bh = xcd * 4 + (loc >> 5);
    int qb = loc & 31;
    int b = bh >> 3, h = bh & 7;
    int qw = qb * 64 + wave * 16;   // this wave's 16 q rows

    const unsigned short* qrow = Q + ((size_t)bh * NS + qw + lrow) * NDK + lgrp * 8;
    bf16x8 aq0 = *(const bf16x8*)(qrow);
    bf16x8 aq1 = *(const bf16x8*)(qrow + 32);

    const unsigned short* kbase = K + (size_t)bh * NS * NDK;
    const unsigned short* vbase = VT + (size_t)bh * NDK * NS;
    const unsigned long long* bmrow = bm + ((size_t)b * NS + qw + lrow) * (NS / 64);

    int rl = lane >> 3, cc = lane & 7;      // staging: slab row (0..7), chunk (0..7)
    int cs = (cc ^ rl) * 8;                 // swizzled source chunk offset (ushorts)
    int r0 = 16 * wave + rl;                // this wave's staging rows: r0 and r0+8
    int plsw = (lrow & 7) << 3;             // pl XOR swizzle (ushort units, 16B granules)

    // ---- sweep 1: l = sum of unmasked exp2(sc); 2 tiles per barrier phase ----
    gload_lds16(kbase + (size_t)r0 * NDK + cs, &kv[0][(16 * wave) * 64]);
    gload_lds16(kbase + (size_t)(r0 + 8) * NDK + cs, &kv[0][(16 * wave + 8) * 64]);
    gload_lds16(kbase + (size_t)(64 + r0) * NDK + cs, &kv[1][(16 * wave) * 64]);
    gload_lds16(kbase + (size_t)(64 + r0 + 8) * NDK + cs, &kv[1][(16 * wave + 8) * 64]);
    unsigned long long wcA = bmrow[0], wcB = bmrow[1];
    asm volatile("s_waitcnt vmcnt(2)" ::: "memory");   // force the 4 K staging calls
    __builtin_amdgcn_s_barrier();

    float lacc = 0.f;
    for (int sp = 0; sp < NT / 2; sp++) {
        int bufA = (2 * sp) & 3, bufB = (2 * sp + 1) & 3;
        unsigned long long wnA = 0, wnB = 0;
        if (sp + 1 < NT / 2) {
            const unsigned short* ka = kbase + (size_t)((2 * sp + 2) * 64) * NDK;
            const unsigned short* kb2 = kbase + (size_t)((2 * sp + 3) * 64) * NDK;
            gload_lds16(ka + (size_t)r0 * NDK + cs, &kv[bufA ^ 2][(16 * wave) * 64]);
            gload_lds16(ka + (size_t)(r0 + 8) * NDK + cs, &kv[bufA ^ 2][(16 * wave + 8) * 64]);
            gload_lds16(kb2 + (size_t)r0 * NDK + cs, &kv[bufB ^ 2][(16 * wave) * 64]);
            gload_lds16(kb2 + (size_t)(r0 + 8) * NDK + cs, &kv[bufB ^ 2][(16 * wave + 8) * 64]);
            wnA = bmrow[2 * sp + 2];
            wnB = bmrow[2 * sp + 3];
        }
#pragma unroll
        for (int half = 0; half < 2; half++) {
            int buf = half == 0 ? bufA : bufB;
            unsigned long long w = half == 0 ? wcA : wcB;
            f32x4 sc[4] = {{0.f,0.f,0.f,0.f},{0.f,0.f,0.f,0.f},{0.f,0.f,0.f,0.f},{0.f,0.f,0.f,0.f}};
            __builtin_amdgcn_s_setprio(1);
#pragma unroll
            for (int n = 0; n < 4; n++) {
                int R = n * 16 + lrow;
                bf16x8 b0 = *(const bf16x8*)&kv[buf][R * 64 + ((lgrp ^ (lrow & 7)) * 8)];
                bf16x8 b1 = *(const bf16x8*)&kv[buf][R * 64 + (((4 + lgrp) ^ (lrow & 7)) * 8)];
                sc[n] = __builtin_amdgcn_mfma_f32_16x16x32_bf16(b0, aq0, sc[n], 0, 0, 0);
                sc[n] = __builtin_amdgcn_mfma_f32_16x16x32_bf16(b1, aq1, sc[n], 0, 0, 0);
            }
            __builtin_amdgcn_s_setprio(0);
            uint32_t wlo = (uint32_t)w, whi = (uint32_t)(w >> 32);
#pragma unroll
            for (int n = 0; n < 4; n++)
#pragma unroll
                for (int j = 0; j < 4; j++) {
                    uint32_t bit = ((n < 2 ? wlo : whi) >> ((n & 1) * 16 + lgrp * 4 + j)) & 1u;
                    float e = exp2_fast(sc[n][j]);
                    lacc += bit ? 0.f : e;
                }
        }
        wcA = wnA; wcB = wnB;
        if (sp + 1 < NT / 2) {
            asm volatile("s_waitcnt vmcnt(2)" ::: "memory");  // force K x4; leave wnA,wnB
            __builtin_amdgcn_s_barrier();
        }
    }
    lacc += __shfl_xor(lacc, 16);
    lacc += __shfl_xor(lacc, 32);
    float li = -__log2f(lacc);

    // ---- sweep 2: recompute, write normalized attn, accumulate O ----
    // K double-buffer in kv[0/1], V double-buffer in kv[2/3]
    gload_lds16(kbase + (size_t)r0 * NDK + cs, &kv[0][(16 * wave) * 64]);
    gload_lds16(kbase + (size_t)(r0 + 8) * NDK + cs, &kv[0][(16 * wave + 8) * 64]);
    gload_lds16(vbase + (size_t)r0 * NS + cs, &kv[2][(16 * wave) * 64]);
    gload_lds16(vbase + (size_t)(r0 + 8) * NS + cs, &kv[2][(16 * wave + 8) * 64]);
    unsigned long long wc = bmrow[0], wn = 0;
    asm volatile("s_waitcnt vmcnt(1)" ::: "memory");   // force the 4 staging calls; wc floats
    __builtin_amdgcn_s_barrier();

    f32x4 accO[4] = {{0.f,0.f,0.f,0.f},{0.f,0.f,0.f,0.f},{0.f,0.f,0.f,0.f},{0.f,0.f,0.f,0.f}};
    float* arow = attn_out + (size_t)bh * NS * NS + (size_t)(qw + lrow) * NS;

    for (int t = 0; t < NT; t++) {
        int buf = t & 1;
        int kt = t * 64;
        if (t + 1 < NT) {
            const unsigned short* kt1 = kbase + (size_t)((t + 1) * 64) * NDK;
            gload_lds16(kt1 + (size_t)r0 * NDK + cs, &kv[buf ^ 1][(16 * wave) * 64]);
            gload_lds16(kt1 + (size_t)(r0 + 8) * NDK + cs, &kv[buf ^ 1][(16 * wave + 8) * 64]);
            const unsigned short* vt1 = vbase + (t + 1) * 64;
            gload_lds16(vt1 + (size_t)r0 * NS + cs, &kv[2 + (buf ^ 1)][(16 * wave) * 64]);
            gload_lds16(vt1 + (size_t)(r0 + 8) * NS + cs, &kv[2 + (buf ^ 1)][(16 * wave + 8) * 64]);
            wn = bmrow[t + 1];
        }
        f32x4 sc[4] = {{0.f,0.f,0.f,0.f},{0.f,0.f,0.f,0.f},{0.f,0.f,0.f,0.f},{0.f,0.f,0.f,0.f}};
        __builtin_amdgcn_s_setprio(1);
#pragma unroll
        for (int n = 0; n < 4; n++) {
            int R = n * 16 + lrow;
            bf16x8 b0 = *(const bf16x8*)&kv[buf][R * 64 + ((lgrp ^ (lrow & 7)) * 8)];
            bf16x8 b1 = *(const bf16x8*)&kv[buf][R * 64 + (((4 + lgrp) ^ (lrow & 7)) * 8)];
            sc[n] = __builtin_amdgcn_mfma_f32_16x16x32_bf16(b0, aq0, sc[n], 0, 0, 0);  // swapped
            sc[n] = __builtin_amdgcn_mfma_f32_16x16x32_bf16(b1, aq1, sc[n], 0, 0, 0);
        }
        __builtin_amdgcn_s_setprio(0);
        uint32_t wlo = (uint32_t)wc, whi = (uint32_t)(wc >> 32);
#pragma unroll
        for (int n = 0; n < 4; n++) {
            float p0, p1, p2, p3;
            uint32_t wsel = (n < 2) ? wlo : whi;
            int base = (n & 1) * 16 + lgrp * 4;
            p0 = ((wsel >> (base + 0)) & 1u) ? 0.f : exp2_fast(sc[n][0] + li);
            p1 = ((wsel >> (base + 1)) & 1u) ? 0.f : exp2_fast(sc[n][1] + li);
            p2 = ((wsel >> (base + 2)) & 1u) ? 0.f : exp2_fast(sc[n][2] + li);
            p3 = ((wsel >> (base + 3)) & 1u) ? 0.f : exp2_fast(sc[n][3] + li);
            f32x4 pv4 = {p0, p1, p2, p3};
            __builtin_nontemporal_store(pv4, (f32x4*)(arow + kt + n * 16 + lgrp * 4));
            uint2 pk = {pkbf(p0, p1), pkbf(p2, p3)};
            *(uint2*)&pl[wave][lrow][(n * 16 + lgrp * 4) ^ plsw] = pk;
        }
        __builtin_amdgcn_s_setprio(1);
#pragma unroll
        for (int step = 0; step < 2; step++) {
            bf16x8 ap = *(const bf16x8*)&pl[wave][lrow][(step * 32 + lgrp * 8) ^ plsw];
#pragma unroll
            for (int n = 0; n < 4; n++) {
                int R = n * 16 + lrow;
                bf16x8 bv = *(const bf16x8*)&kv[2 + buf][R * 64 + (((4 * step + lgrp) ^ (lrow & 7)) * 8)];
                accO[n] = __builtin_amdgcn_mfma_f32_16x16x32_bf16(ap, bv, accO[n], 0, 0, 0);
            }
        }
        __builtin_amdgcn_s_setprio(0);
        wc = wn;
        if (t + 1 < NT) {
            // queue: [K x2, V x2, wn, 4 stores] -> force the 4 staging loads, leave wn + stores
            asm volatile("s_waitcnt vmcnt(5)" ::: "memory");
            __builtin_amdgcn_s_barrier();
        }
    }

#pragma unroll
    for (int n = 0; n < 4; n++)
#pragma unroll
        for (int j = 0; j < 4; j++) {
            int qi = qw + lgrp * 4 + j;
            Ob[((size_t)b * NS + qi) * ND + h * NDK + n * 16 + lrow] = accO[n][j];
        }
}

// ---------------- residual + LayerNorm (OpenNMT: unbiased std, eps on std) ----------------
__global__ __launch_bounds__(256) void ln_kernel(const float* __restrict__ Ob,
                                                 const float* __restrict__ query,
                                                 const float* __restrict__ a2,
                                                 const float* __restrict__ b2,
                                                 float* __restrict__ out) {
    int row = blockIdx.x * 4 + (threadIdx.x >> 6);
    int lane = threadIdx.x & 63;
    const float4* orow = (const float4*)(Ob + (size_t)row * ND);
    const float4* qrow = (const float4*)(query + (size_t)row * ND);
    float4 v[2];
    float sum = 0.f;
#pragma unroll
    for (int t = 0; t < 2; t++) {
        float4 o = orow[lane + t * 64];
        float4 q = qrow[lane + t * 64];
        v[t].x = o.x + q.x; v[t].y = o.y + q.y; v[t].z = o.z + q.z; v[t].w = o.w + q.w;
        sum += v[t].x + v[t].y + v[t].z + v[t].w;
    }
#pragma unroll
    for (int s = 1; s < 64; s <<= 1) sum += __shfl_xor(sum, s);
    float mu = sum * (1.f / ND);
    float sq = 0.f;
#pragma unroll
    for (int t = 0; t < 2; t++) {
        float dx = v[t].x - mu, dy = v[t].y - mu, dz = v[t].z - mu, dw = v[t].w - mu;
        sq += dx * dx + dy * dy + dz * dz + dw * dw;
    }
#pragma unroll
    for (int s = 1; s < 64; s <<= 1) sq += __shfl_xor(sq, s);
    float var = sq * (1.f / (ND - 1));
    float inv = 1.f / (sqrtf(var) + 1e-6f);
    float4* orow_out = (float4*)(out + (size_t)row * ND);
#pragma unroll
    for (int t = 0; t < 2; t++) {
        float4 g = ((const float4*)a2)[lane + t * 64];
        float4 bb = ((const float4*)b2)[lane + t * 64];
        float4 r;
        r.x = g.x * (v[t].x - mu) * inv + bb.x;
        r.y = g.y * (v[t].y - mu) * inv + bb.y;
        r.z = g.z * (v[t].z - mu) * inv + bb.z;
        r.w = g.w * (v[t].w - mu) * inv + bb.w;
        orow_out[lane + t * 64] = r;
    }
}

extern "C" void kernel_launch(void* const* d_in, const int* in_sizes, int n_in,
                              void* d_out, int out_size, void* d_ws, size_t ws_size,
                              hipStream_t stream) {
    const float* key   = (const float*)d_in[0];
    const float* value = (const float*)d_in[1];
    const float* query = (const float*)d_in[2];
    const int*   mask  = (const int*)d_in[3];
    const float* Wk = (const float*)d_in[4];
    const float* bk = (const float*)d_in[5];
    const float* Wv = (const float*)d_in[6];
    const float* bv = (const float*)d_in[7];
    const float* Wq = (const float*)d_in[8];
    const float* bq = (const float*)d_in[9];
    const float* a2 = (const float*)d_in[10];
    const float* b2 = (const float*)d_in[11];

    const size_t nX = (size_t)NB * NS * ND;   // 4,194,304
    const size_t nW = (size_t)ND * ND;        // 262,144
    const int    nBMw = NB * NS * NS / 64;    // 262,144 uint64 words

    unsigned short* xq  = (unsigned short*)d_ws;  // bf16 buffers
    unsigned short* xk  = xq + nX;
    unsigned short* xv  = xk + nX;
    unsigned short* wqb = xv + nX;
    unsigned short* wkb = wqb + nW;
    unsigned short* wvb = wkb + nW;
    unsigned short* Qw  = wvb + nW;               // [BH][S][dk]
    unsigned short* Kw  = Qw + nX;                // [BH][S][dk]
    unsigned short* VTw = Kw + nX;                // [BH][dk][S]
    float* Ow = (float*)(VTw + nX);               // [B][S][D] fp32
    unsigned long long* bmw = (unsigned long long*)(Ow + nX);  // bitmask, 2 MB

    bitmask_kernel<<<2048, 256, 0, stream>>>(mask, bmw, nBMw);

    cvt3_kernel<<<dim3((int)(nX / 4 / 256), 3), 256, 0, stream>>>(
        (const float4*)query, (const float4*)key, (const float4*)value,
        (ushort4*)xq, (ushort4*)xk, (ushort4*)xv, (int)(nX / 4));
    cvt3_kernel<<<dim3((int)(nW / 4 / 256), 3), 256, 0, stream>>>(
        (const float4*)Wq, (const float4*)Wk, (const float4*)Wv,
        (ushort4*)wqb, (ushort4*)wkb, (ushort4*)wvb, (int)(nW / 4));

    proj_kernel<<<dim3(128, 8, 3), 256, 0, stream>>>(xq, xk, xv, wqb, wkb, wvb,
                                                     bq, bk, bv, Qw, Kw, VTw);

    float* attn_out = (float*)d_out + nX;  // res occupies first nX floats
    attn_kernel<<<1024, 256, 0, stream>>>(Qw, Kw, VTw, bmw, attn_out, Ow);

    ln_kernel<<<2048, 256, 0, stream>>>(Ow, query, a2, b2, (float*)d_out);
}

// Round 15
// 344.062 us; speedup vs baseline: 1.0731x; 1.0059x over previous
//
#include <hip/hip_runtime.h>
#include <stdint.h>

typedef float f32x4 __attribute__((ext_vector_type(4)));
typedef short bf16x8 __attribute__((ext_vector_type(8)));

constexpr int NB = 4;      // batch
constexpr int NS = 2048;   // sequence
constexpr int ND = 512;    // model dim
constexpr int NH = 8;      // heads
constexpr int NDK = 64;    // head dim
constexpr int NT = NS / 64;  // 32 K-tiles
constexpr float QSCALE = 0.125f * 1.44269504088896340736f;  // 1/sqrt(dk) * log2(e)

static __device__ __forceinline__ unsigned short f2bf(float f) {
    union { float f; uint32_t u; } v; v.f = f;
    uint32_t r = (v.u + 0x7FFFu + ((v.u >> 16) & 1u)) >> 16;
    return (unsigned short)r;
}
static __device__ __forceinline__ uint32_t pkbf(float a, float b) {
    union { float f; uint32_t u; } x, y; x.f = a; y.f = b;
    return ((x.u + 0x8000u) >> 16) | (((y.u + 0x8000u) >> 16) << 16);
}
static __device__ __forceinline__ float exp2_fast(float x) {
#if __has_builtin(__builtin_amdgcn_exp2f)
    return __builtin_amdgcn_exp2f(x);
#else
    return exp2f(x);
#endif
}

// async global->LDS, 16B per lane; dest is wave-uniform base (+lane*16 by HW)
static __device__ __forceinline__ void gload_lds16(const void* g, void* l) {
    __builtin_amdgcn_global_load_lds((const __attribute__((address_space(1))) void*)g,
                                     (__attribute__((address_space(3))) void*)l, 16, 0, 0);
}

// ---------------- fused prep: fp32->bf16 cvt (q,k,v,Wq,Wk,Wv) + mask bitmask ----------------
// Independent memory-bound work merged into ONE launch: removes 2 full-GPU drain
// boundaries and overlaps the 67MB mask read with the cvt streams.
// Block ranges: [0,12288) cvt big (3 x 4096), [12288,13056) cvt W (3 x 256),
// [13056,15104) bitmask (2048, grid-stride).
__global__ __launch_bounds__(256) void prep_kernel(const float4* __restrict__ q,
                                                   const float4* __restrict__ k,
                                                   const float4* __restrict__ v,
                                                   const float4* __restrict__ wq,
                                                   const float4* __restrict__ wk,
                                                   const float4* __restrict__ wv,
                                                   ushort4* __restrict__ oq,
                                                   ushort4* __restrict__ ok,
                                                   ushort4* __restrict__ ov,
                                                   ushort4* __restrict__ owq,
                                                   ushort4* __restrict__ owk,
                                                   ushort4* __restrict__ owv,
                                                   const int* __restrict__ mask,
                                                   unsigned long long* __restrict__ bm,
                                                   int nBMw) {
    int bid = blockIdx.x;
    if (bid < 12288) {
        int which = bid >> 12;
        int i = ((bid & 4095) << 8) + threadIdx.x;
        const float4* in = which == 0 ? q : which == 1 ? k : v;
        ushort4* out = which == 0 ? oq : which == 1 ? ok : ov;
        float4 x = in[i];
        ushort4 o;
        o.x = f2bf(x.x); o.y = f2bf(x.y); o.z = f2bf(x.z); o.w = f2bf(x.w);
        out[i] = o;
    } else if (bid < 13056) {
        int r = bid - 12288;
        int which = r >> 8;
        int i = ((r & 255) << 8) + threadIdx.x;
        const float4* in = which == 0 ? wq : which == 1 ? wk : wv;
        ushort4* out = which == 0 ? owq : which == 1 ? owk : owv;
        float4 x = in[i];
        ushort4 o;
        o.x = f2bf(x.x); o.y = f2bf(x.y); o.z = f2bf(x.z); o.w = f2bf(x.w);
        out[i] = o;
    } else {
        int r = bid - 13056;              // 0..2047
        int lane = threadIdx.x & 63;
        int wave = threadIdx.x >> 6;
        int wgid = r * 4 + wave;
        int nw = 2048 * 4;
        for (int c = wgid; c < nBMw; c += nw) {
            int m = mask[(size_t)c * 64 + lane];
            unsigned long long bits = __ballot(m != 0);
            if (lane == 0) bm[c] = bits;
        }
    }
}

// ---------------- fused projections: z=0 Q (scale QSCALE), z=1 K, z=2 V (transposed out) -----
__global__ __launch_bounds__(256) void proj_kernel(const unsigned short* __restrict__ xq,
                                                   const unsigned short* __restrict__ xk,
                                                   const unsigned short* __restrict__ xv,
                                                   const unsigned short* __restrict__ wq,
                                                   const unsigned short* __restrict__ wk,
                                                   const unsigned short* __restrict__ wv,
                                                   const float* __restrict__ bq,
                                                   const float* __restrict__ bk,
                                                   const float* __restrict__ bv,
                                                   unsigned short* __restrict__ Qw,
                                                   unsigned short* __restrict__ Kw,
                                                   unsigned short* __restrict__ VTw) {
    int z = blockIdx.z;
    const unsigned short* X = z == 0 ? xq : z == 1 ? xk : xv;
    const unsigned short* W = z == 0 ? wq : z == 1 ? wk : wv;
    const float* bias = z == 0 ? bq : z == 1 ? bk : bv;
    unsigned short* out = z == 0 ? Qw : z == 1 ? Kw : VTw;
    float scale = z == 0 ? QSCALE : 1.0f;
    int vtrans = (z == 2);

    int lane = threadIdx.x & 63;
    int wave = threadIdx.x >> 6;
    int lrow = lane & 15, lgrp = lane >> 4;
    int m0 = blockIdx.x * 64 + wave * 16;
    int n0 = blockIdx.y * 64;

    f32x4 acc[4] = {{0.f,0.f,0.f,0.f},{0.f,0.f,0.f,0.f},{0.f,0.f,0.f,0.f},{0.f,0.f,0.f,0.f}};
    const unsigned short* xrow = X + (size_t)(m0 + lrow) * ND;
    for (int k = 0; k < ND; k += 32) {
        bf16x8 a = *(const bf16x8*)(xrow + k + lgrp * 8);
#pragma unroll
        for (int n = 0; n < 4; n++) {
            bf16x8 b = *(const bf16x8*)(W + (size_t)(n0 + n * 16 + lrow) * ND + k + lgrp * 8);
            acc[n] = __builtin_amdgcn_mfma_f32_16x16x32_bf16(a, b, acc[n], 0, 0, 0);
        }
    }
#pragma unroll
    for (int n = 0; n < 4; n++) {
        int col = n0 + n * 16 + lrow;
        int h = col >> 6, d = col & 63;
        float bv_ = bias[col];
#pragma unroll
        for (int j = 0; j < 4; j++) {
            int m = m0 + lgrp * 4 + j;
            int bidx = m >> 11, s = m & (NS - 1);
            float y = (acc[n][j] + bv_) * scale;
            size_t off = vtrans ? ((size_t)(bidx * NH + h) * NDK + d) * NS + s
                                : ((size_t)(bidx * NH + h) * NS + s) * NDK + d;
            out[off] = f2bf(y);
        }
    }
}

// ---------------- attention ----------------
// 256 threads = 4 waves; block owns 64 q-rows, full K range; 4 blocks/CU (40KB LDS).
// Q pre-scaled by log2e/8. SWAPPED QK^T: lane holds qi = lane&15 fixed, ki = n*16+lgrp*4+j.
// kv[4] buffer pool: sweep 1 = 4-deep K ring, 2 tiles per barrier phase; sweep 2 =
// K dbuf kv[0/1] + V dbuf kv[2/3]. XOR-swizzled staging. Raw s_barrier + counted vmcnt.
// attn stores NONTEMPORAL: no-allocate protects per-XCD L2 K/V residency (round-13 A/B:
// plain stores +22us despite line-merge benefit).
__global__ __launch_bounds__(256) void attn_kernel(const unsigned short* __restrict__ Q,
                                                   const unsigned short* __restrict__ K,
                                                   const unsigned short* __restrict__ VT,
                                                   const unsigned long long* __restrict__ bm,
                                                   float* __restrict__ attn_out,
                                                   float* __restrict__ Ob) {
    __shared__ __align__(16) unsigned short kv[4][64 * 64];   // 32KB buffer pool
    __shared__ __align__(16) unsigned short pl[4][16][64];    // 8KB per-wave P tile, XOR-swizzled

    int lane = threadIdx.x & 63;
    int wave = threadIdx.x >> 6;      // 0..3
    int lrow = lane & 15, lgrp = lane >> 4;

    // XCD-aware remap: id&7 = xcd, 4 bh per xcd, 32 q-blocks per bh
    int id = blockIdx.x;
    int xcd = id & 7;
    int loc = id >> 3;            // 0..127
    int bh = xcd * 4 + (loc >> 5);
    int qb = loc & 31;
    int b = bh >> 3, h = bh & 7;
    int qw = qb * 64 + wave * 16;   // this wave's 16 q rows

    const unsigned short* qrow = Q + ((size_t)bh * NS + qw + lrow) * NDK + lgrp * 8;
    bf16x8 aq0 = *(const bf16x8*)(qrow);
    bf16x8 aq1 = *(const bf16x8*)(qrow + 32);

    const unsigned short* kbase = K + (size_t)bh * NS * NDK;
    const unsigned short* vbase = VT + (size_t)bh * NDK * NS;
    const unsigned long long* bmrow = bm + ((size_t)b * NS + qw + lrow) * (NS / 64);

    int rl = lane >> 3, cc = lane & 7;      // staging: slab row (0..7), chunk (0..7)
    int cs = (cc ^ rl) * 8;                 // swizzled source chunk offset (ushorts)
    int r0 = 16 * wave + rl;                // this wave's staging rows: r0 and r0+8
    int plsw = (lrow & 7) << 3;             // pl XOR swizzle (ushort units, 16B granules)

    // ---- sweep 1: l = sum of unmasked exp2(sc); 2 tiles per barrier phase ----
    gload_lds16(kbase + (size_t)r0 * NDK + cs, &kv[0][(16 * wave) * 64]);
    gload_lds16(kbase + (size_t)(r0 + 8) * NDK + cs, &kv[0][(16 * wave + 8) * 64]);
    gload_lds16(kbase + (size_t)(64 + r0) * NDK + cs, &kv[1][(16 * wave) * 64]);
    gload_lds16(kbase + (size_t)(64 + r0 + 8) * NDK + cs, &kv[1][(16 * wave + 8) * 64]);
    unsigned long long wcA = bmrow[0], wcB = bmrow[1];
    asm volatile("s_waitcnt vmcnt(2)" ::: "memory");   // force the 4 K staging calls
    __builtin_amdgcn_s_barrier();

    float lacc = 0.f;
    for (int sp = 0; sp < NT / 2; sp++) {
        int bufA = (2 * sp) & 3, bufB = (2 * sp + 1) & 3;
        unsigned long long wnA = 0, wnB = 0;
        if (sp + 1 < NT / 2) {
            const unsigned short* ka = kbase + (size_t)((2 * sp + 2) * 64) * NDK;
            const unsigned short* kb2 = kbase + (size_t)((2 * sp + 3) * 64) * NDK;
            gload_lds16(ka + (size_t)r0 * NDK + cs, &kv[bufA ^ 2][(16 * wave) * 64]);
            gload_lds16(ka + (size_t)(r0 + 8) * NDK + cs, &kv[bufA ^ 2][(16 * wave + 8) * 64]);
            gload_lds16(kb2 + (size_t)r0 * NDK + cs, &kv[bufB ^ 2][(16 * wave) * 64]);
            gload_lds16(kb2 + (size_t)(r0 + 8) * NDK + cs, &kv[bufB ^ 2][(16 * wave + 8) * 64]);
            wnA = bmrow[2 * sp + 2];
            wnB = bmrow[2 * sp + 3];
        }
#pragma unroll
        for (int half = 0; half < 2; half++) {
            int buf = half == 0 ? bufA : bufB;
            unsigned long long w = half == 0 ? wcA : wcB;
            f32x4 sc[4] = {{0.f,0.f,0.f,0.f},{0.f,0.f,0.f,0.f},{0.f,0.f,0.f,0.f},{0.f,0.f,0.f,0.f}};
            __builtin_amdgcn_s_setprio(1);
#pragma unroll
            for (int n = 0; n < 4; n++) {
                int R = n * 16 + lrow;
                bf16x8 b0 = *(const bf16x8*)&kv[buf][R * 64 + ((lgrp ^ (lrow & 7)) * 8)];
                bf16x8 b1 = *(const bf16x8*)&kv[buf][R * 64 + (((4 + lgrp) ^ (lrow & 7)) * 8)];
                sc[n] = __builtin_amdgcn_mfma_f32_16x16x32_bf16(b0, aq0, sc[n], 0, 0, 0);
                sc[n] = __builtin_amdgcn_mfma_f32_16x16x32_bf16(b1, aq1, sc[n], 0, 0, 0);
            }
            __builtin_amdgcn_s_setprio(0);
            uint32_t wlo = (uint32_t)w, whi = (uint32_t)(w >> 32);
#pragma unroll
            for (int n = 0; n < 4; n++)
#pragma unroll
                for (int j = 0; j < 4; j++) {
                    uint32_t bit = ((n < 2 ? wlo : whi) >> ((n & 1) * 16 + lgrp * 4 + j)) & 1u;
                    float e = exp2_fast(sc[n][j]);
                    lacc += bit ? 0.f : e;
                }
        }
        wcA = wnA; wcB = wnB;
        if (sp + 1 < NT / 2) {
            asm volatile("s_waitcnt vmcnt(2)" ::: "memory");  // force K x4; leave wnA,wnB
            __builtin_amdgcn_s_barrier();
        }
    }
    lacc += __shfl_xor(lacc, 16);
    lacc += __shfl_xor(lacc, 32);
    float li = -__log2f(lacc);

    // ---- sweep 2: recompute, write normalized attn, accumulate O ----
    // K double-buffer in kv[0/1], V double-buffer in kv[2/3]
    gload_lds16(kbase + (size_t)r0 * NDK + cs, &kv[0][(16 * wave) * 64]);
    gload_lds16(kbase + (size_t)(r0 + 8) * NDK + cs, &kv[0][(16 * wave + 8) * 64]);
    gload_lds16(vbase + (size_t)r0 * NS + cs, &kv[2][(16 * wave) * 64]);
    gload_lds16(vbase + (size_t)(r0 + 8) * NS + cs, &kv[2][(16 * wave + 8) * 64]);
    unsigned long long wc = bmrow[0], wn = 0;
    asm volatile("s_waitcnt vmcnt(1)" ::: "memory");   // force the 4 staging calls; wc floats
    __builtin_amdgcn_s_barrier();

    f32x4 accO[4] = {{0.f,0.f,0.f,0.f},{0.f,0.f,0.f,0.f},{0.f,0.f,0.f,0.f},{0.f,0.f,0.f,0.f}};
    float* arow = attn_out + (size_t)bh * NS * NS + (size_t)(qw + lrow) * NS;

    for (int t = 0; t < NT; t++) {
        int buf = t & 1;
        int kt = t * 64;
        if (t + 1 < NT) {
            const unsigned short* kt1 = kbase + (size_t)((t + 1) * 64) * NDK;
            gload_lds16(kt1 + (size_t)r0 * NDK + cs, &kv[buf ^ 1][(16 * wave) * 64]);
            gload_lds16(kt1 + (size_t)(r0 + 8) * NDK + cs, &kv[buf ^ 1][(16 * wave + 8) * 64]);
            const unsigned short* vt1 = vbase + (t + 1) * 64;
            gload_lds16(vt1 + (size_t)r0 * NS + cs, &kv[2 + (buf ^ 1)][(16 * wave) * 64]);
            gload_lds16(vt1 + (size_t)(r0 + 8) * NS + cs, &kv[2 + (buf ^ 1)][(16 * wave + 8) * 64]);
            wn = bmrow[t + 1];
        }
        f32x4 sc[4] = {{0.f,0.f,0.f,0.f},{0.f,0.f,0.f,0.f},{0.f,0.f,0.f,0.f},{0.f,0.f,0.f,0.f}};
        __builtin_amdgcn_s_setprio(1);
#pragma unroll
        for (int n = 0; n < 4; n++) {
            int R = n * 16 + lrow;
            bf16x8 b0 = *(const bf16x8*)&kv[buf][R * 64 + ((lgrp ^ (lrow & 7)) * 8)];
            bf16x8 b1 = *(const bf16x8*)&kv[buf][R * 64 + (((4 + lgrp) ^ (lrow & 7)) * 8)];
            sc[n] = __builtin_amdgcn_mfma_f32_16x16x32_bf16(b0, aq0, sc[n], 0, 0, 0);  // swapped
            sc[n] = __builtin_amdgcn_mfma_f32_16x16x32_bf16(b1, aq1, sc[n], 0, 0, 0);
        }
        __builtin_amdgcn_s_setprio(0);
        uint32_t wlo = (uint32_t)wc, whi = (uint32_t)(wc >> 32);
#pragma unroll
        for (int n = 0; n < 4; n++) {
            float p0, p1, p2, p3;
            uint32_t wsel = (n < 2) ? wlo : whi;
            int base = (n & 1) * 16 + lgrp * 4;
            p0 = ((wsel >> (base + 0)) & 1u) ? 0.f : exp2_fast(sc[n][0] + li);
            p1 = ((wsel >> (base + 1)) & 1u) ? 0.f : exp2_fast(sc[n][1] + li);
            p2 = ((wsel >> (base + 2)) & 1u) ? 0.f : exp2_fast(sc[n][2] + li);
            p3 = ((wsel >> (base + 3)) & 1u) ? 0.f : exp2_fast(sc[n][3] + li);
            f32x4 pv4 = {p0, p1, p2, p3};
            __builtin_nontemporal_store(pv4, (f32x4*)(arow + kt + n * 16 + lgrp * 4));
            uint2 pk = {pkbf(p0, p1), pkbf(p2, p3)};
            *(uint2*)&pl[wave][lrow][(n * 16 + lgrp * 4) ^ plsw] = pk;
        }
        __builtin_amdgcn_s_setprio(1);
#pragma unroll
        for (int step = 0; step < 2; step++) {
            bf16x8 ap = *(const bf16x8*)&pl[wave][lrow][(step * 32 + lgrp * 8) ^ plsw];
#pragma unroll
            for (int n = 0; n < 4; n++) {
                int R = n * 16 + lrow;
                bf16x8 bv = *(const bf16x8*)&kv[2 + buf][R * 64 + (((4 * step + lgrp) ^ (lrow & 7)) * 8)];
                accO[n] = __builtin_amdgcn_mfma_f32_16x16x32_bf16(ap, bv, accO[n], 0, 0, 0);
            }
        }
        __builtin_amdgcn_s_setprio(0);
        wc = wn;
        if (t + 1 < NT) {
            // queue: [K x2, V x2, wn, 4 stores] -> force the 4 staging loads, leave wn + stores
            asm volatile("s_waitcnt vmcnt(5)" ::: "memory");
            __builtin_amdgcn_s_barrier();
        }
    }

#pragma unroll
    for (int n = 0; n < 4; n++)
#pragma unroll
        for (int j = 0; j < 4; j++) {
            int qi = qw + lgrp * 4 + j;
            Ob[((size_t)b * NS + qi) * ND + h * NDK + n * 16 + lrow] = accO[n][j];
        }
}

// ---------------- residual + LayerNorm (OpenNMT: unbiased std, eps on std) ----------------
__global__ __launch_bounds__(256) void ln_kernel(const float* __restrict__ Ob,
                                                 const float* __restrict__ query,
                                                 const float* __restrict__ a2,
                                                 const float* __restrict__ b2,
                                                 float* __restrict__ out) {
    int row = blockIdx.x * 4 + (threadIdx.x >> 6);
    int lane = threadIdx.x & 63;
    const float4* orow = (const float4*)(Ob + (size_t)row * ND);
    const float4* qrow = (const float4*)(query + (size_t)row * ND);
    float4 v[2];
    float sum = 0.f;
#pragma unroll
    for (int t = 0; t < 2; t++) {
        float4 o = orow[lane + t * 64];
        float4 q = qrow[lane + t * 64];
        v[t].x = o.x + q.x; v[t].y = o.y + q.y; v[t].z = o.z + q.z; v[t].w = o.w + q.w;
        sum += v[t].x + v[t].y + v[t].z + v[t].w;
    }
#pragma unroll
    for (int s = 1; s < 64; s <<= 1) sum += __shfl_xor(sum, s);
    float mu = sum * (1.f / ND);
    float sq = 0.f;
#pragma unroll
    for (int t = 0; t < 2; t++) {
        float dx = v[t].x - mu, dy = v[t].y - mu, dz = v[t].z - mu, dw = v[t].w - mu;
        sq += dx * dx + dy * dy + dz * dz + dw * dw;
    }
#pragma unroll
    for (int s = 1; s < 64; s <<= 1) sq += __shfl_xor(sq, s);
    float var = sq * (1.f / (ND - 1));
    float inv = 1.f / (sqrtf(var) + 1e-6f);
    float4* orow_out = (float4*)(out + (size_t)row * ND);
#pragma unroll
    for (int t = 0; t < 2; t++) {
        float4 g = ((const float4*)a2)[lane + t * 64];
        float4 bb = ((const float4*)b2)[lane + t * 64];
        float4 r;
        r.x = g.x * (v[t].x - mu) * inv + bb.x;
        r.y = g.y * (v[t].y - mu) * inv + bb.y;
        r.z = g.z * (v[t].z - mu) * inv + bb.z;
        r.w = g.w * (v[t].w - mu) * inv + bb.w;
        orow_out[lane + t * 64] = r;
    }
}

extern "C" void kernel_launch(void* const* d_in, const int* in_sizes, int n_in,
                              void* d_out, int out_size, void* d_ws, size_t ws_size,
                              hipStream_t stream) {
    const float* key   = (const float*)d_in[0];
    const float* value = (const float*)d_in[1];
    const float* query = (const float*)d_in[2];
    const int*   mask  = (const int*)d_in[3];
    const float* Wk = (const float*)d_in[4];
    const float* bk = (const float*)d_in[5];
    const float* Wv = (const float*)d_in[6];
    const float* bv = (const float*)d_in[7];
    const float* Wq = (const float*)d_in[8];
    const float* bq = (const float*)d_in[9];
    const float* a2 = (const float*)d_in[10];
    const float* b2 = (const float*)d_in[11];

    const size_t nX = (size_t)NB * NS * ND;   // 4,194,304
    const size_t nW = (size_t)ND * ND;        // 262,144
    const int    nBMw = NB * NS * NS / 64;    // 262,144 uint64 words

    unsigned short* xq  = (unsigned short*)d_ws;  // bf16 buffers
    unsigned short* xk  = xq + nX;
    unsigned short* xv  = xk + nX;
    unsigned short* wqb = xv + nX;
    unsigned short* wkb = wqb + nW;
    unsigned short* wvb = wkb + nW;
    unsigned short* Qw  = wvb + nW;               // [BH][S][dk]
    unsigned short* Kw  = Qw + nX;                // [BH][S][dk]
    unsigned short* VTw = Kw + nX;                // [BH][dk][S]
    float* Ow = (float*)(VTw + nX);               // [B][S][D] fp32
    unsigned long long* bmw = (unsigned long long*)(Ow + nX);  // bitmask, 2 MB

    // fused prep: 12288 cvt-big + 768 cvt-W + 2048 bitmask blocks in one launch
    prep_kernel<<<15104, 256, 0, stream>>>(
        (const float4*)query, (const float4*)key, (const float4*)value,
        (const float4*)Wq, (const float4*)Wk, (const float4*)Wv,
        (ushort4*)xq, (ushort4*)xk, (ushort4*)xv,
        (ushort4*)wqb, (ushort4*)wkb, (ushort4*)wvb,
        mask, bmw, nBMw);

    proj_kernel<<<dim3(128, 8, 3), 256, 0, stream>>>(xq, xk, xv, wqb, wkb, wvb,
                                                     bq, bk, bv, Qw, Kw, VTw);

    float* attn_out = (float*)d_out + nX;  // res occupies first nX floats
    attn_kernel<<<1024, 256, 0, stream>>>(Qw, Kw, VTw, bmw, attn_out, Ow);

    ln_kernel<<<2048, 256, 0, stream>>>(Ow, query, a2, b2, (float*)d_out);
}